// Round 5
// baseline (1008.542 us; speedup 1.0000x reference)
//
#include <hip/hip_runtime.h>
#include <hip/hip_cooperative_groups.h>
namespace cg = cooperative_groups;

// ---------------- constants ----------------
#define SS    4096
#define HH    2048
#define NQQ   18
#define QH    72
#define SCALE_F 0.044194173824159216f   // 1/sqrt(512)

// output regions (f32 elements)
#define OUT_MEM     0
#define OUT_PRI     131072
#define OUT_CONF    131136
#define OUT_VAL     131140
#define OUT_ENT     131144
#define OUT_NEWPRI  393288

typedef float  f32x4  __attribute__((ext_vector_type(4)));
typedef __bf16 bf16x8 __attribute__((ext_vector_type(8)));

#define DEVFN static __device__ __forceinline__

DEVFN bf16x8 pack8(f32x4 lo, f32x4 hi){
  bf16x8 r;
  #pragma unroll
  for (int i = 0; i < 4; i++){ r[i] = (__bf16)lo[i]; r[i+4] = (__bf16)hi[i]; }
  return r;
}
DEVFN float siluf(float x){ return x / (1.f + expf(-x)); }
DEVFN float block_sum(float v, float* sb){   // 256 threads
  #pragma unroll
  for (int o = 32; o > 0; o >>= 1) v += __shfl_xor(v, o);
  int wid = threadIdx.x >> 6, lane = threadIdx.x & 63;
  if (lane == 0) sb[wid] = v;
  __syncthreads();
  v = sb[0] + sb[1] + sb[2] + sb[3];
  __syncthreads();
  return v;
}

// ======== GEMM-BT body: Cp[y][Mp][N] = A_bf16(Mp,Kf) @ B_f32(N,Kf)^T ========
template<int MF, int KC, bool HSEL>
DEVFN void gemm_bt_body(int bx, int by, bool zsel,
    const __bf16* __restrict__ A, int Kf,
    const float* __restrict__ B0, float* __restrict__ C0,
    const float* __restrict__ B1, float* __restrict__ C1,
    int N)
{
  constexpr int Mp = 16 * MF;
  const int lane = threadIdx.x & 63, w = threadIdx.x >> 6;
  const int n0 = bx * 64 + w * 16;
  const int k0 = by * KC * 32;
  const float* B = zsel ? B1 : B0;
  float* Cp      = zsel ? C1 : C0;
  const __bf16* aBase = A + (HSEL ? (long)(n0 >> 9) * Mp * Kf : 0)
                          + (long)(lane & 15) * Kf + k0 + 8 * (lane >> 4);
  const float* bBase = B + (long)(n0 + (lane & 15)) * Kf + k0 + 8 * (lane >> 4);
  f32x4 acc[MF];
  #pragma unroll
  for (int m = 0; m < MF; m++) acc[m] = (f32x4)(0.f);
  #pragma unroll 4
  for (int c = 0; c < KC; c++){
    f32x4 lo = *reinterpret_cast<const f32x4*>(bBase + c * 32);
    f32x4 hi = *reinterpret_cast<const f32x4*>(bBase + c * 32 + 4);
    bf16x8 bb = pack8(lo, hi);
    #pragma unroll
    for (int m = 0; m < MF; m++){
      bf16x8 aa = *reinterpret_cast<const bf16x8*>(aBase + (long)m * 16 * Kf + c * 32);
      acc[m] = __builtin_amdgcn_mfma_f32_16x16x32_bf16(aa, bb, acc[m], 0, 0, 0);
    }
  }
  float* cp = Cp + (long)by * Mp * N;
  int row0 = 4 * (lane >> 4), col = n0 + (lane & 15);
  #pragma unroll
  for (int m = 0; m < MF; m++)
    #pragma unroll
    for (int r = 0; r < 4; r++)
      cp[(long)(m * 16 + row0 + r) * N + col] = acc[m][r];
}

// ======== GEMM-ABNAT body: Cp[z][y][Mp][N] = A_bf16(z) @ Bn_f32(z)(K,N) ========
template<int MF, int KC>
DEVFN void gemm_abnat_body(int bx, int by, int bz,
    const __bf16* __restrict__ A, long aBatch, int aStride,
    const float* __restrict__ Bn, long bBatch,
    float* __restrict__ Cp, long cBatch,
    int N)
{
  constexpr int Mp = 16 * MF;
  const int lane = threadIdx.x & 63, w = threadIdx.x >> 6;
  const int n0 = bx * 64 + w * 16;
  const int k0 = by * KC * 32;
  const __bf16* aBase = A + bz * aBatch + (long)(lane & 15) * aStride + k0 + 8 * (lane >> 4);
  const float* bBase = Bn + bz * bBatch + (long)(k0 + 8 * (lane >> 4)) * N + n0 + (lane & 15);
  f32x4 acc[MF];
  #pragma unroll
  for (int m = 0; m < MF; m++) acc[m] = (f32x4)(0.f);
  #pragma unroll 2
  for (int c = 0; c < KC; c++){
    const float* bp = bBase + (long)c * 32 * N;
    bf16x8 bb;
    #pragma unroll
    for (int j = 0; j < 8; j++) bb[j] = (__bf16)bp[(long)j * N];
    #pragma unroll
    for (int m = 0; m < MF; m++){
      bf16x8 aa = *reinterpret_cast<const bf16x8*>(aBase + (long)m * 16 * aStride + c * 32);
      acc[m] = __builtin_amdgcn_mfma_f32_16x16x32_bf16(aa, bb, acc[m], 0, 0, 0);
    }
  }
  float* cp = Cp + bz * cBatch + (long)by * Mp * N;
  int row0 = 4 * (lane >> 4), col = n0 + (lane & 15);
  #pragma unroll
  for (int m = 0; m < MF; m++)
    #pragma unroll
    for (int r = 0; r < 4; r++)
      cp[(long)(m * 16 + row0 + r) * N + col] = acc[m][r];
}

// ======== standalone: pass1, abnat (pass3), softmax (verified round 4) ========
template<int KC>
__global__ __launch_bounds__(256) void gemm_pass1(
    const float* __restrict__ hs, const __bf16* __restrict__ qk,
    float* __restrict__ Sp)
{
  const int lane = threadIdx.x & 63, w = threadIdx.x >> 6;
  const int b = blockIdx.z;
  const int s0 = blockIdx.x * 64 + w * 16;
  const int k0 = blockIdx.y * KC * 32;
  const float* aBase = hs + ((long)b * SS + s0 + (lane & 15)) * HH + k0 + 8 * (lane >> 4);
  const __bf16* bBase = qk + (long)(lane & 15) * HH + k0 + 8 * (lane >> 4);
  f32x4 acc[5];
  #pragma unroll
  for (int n = 0; n < 5; n++) acc[n] = (f32x4)(0.f);
  #pragma unroll 4
  for (int c = 0; c < KC; c++){
    f32x4 lo = *reinterpret_cast<const f32x4*>(aBase + c * 32);
    f32x4 hi = *reinterpret_cast<const f32x4*>(aBase + c * 32 + 4);
    bf16x8 aa = pack8(lo, hi);
    #pragma unroll
    for (int n = 0; n < 5; n++){
      bf16x8 bb = *reinterpret_cast<const bf16x8*>(bBase + (long)n * 16 * HH + c * 32);
      acc[n] = __builtin_amdgcn_mfma_f32_16x16x32_bf16(aa, bb, acc[n], 0, 0, 0);
    }
  }
  float* sp = Sp + ((long)blockIdx.y * 4 + b) * 80 * SS;
  int scol = s0 + 4 * (lane >> 4);
  #pragma unroll
  for (int n = 0; n < 5; n++){
    int qh = n * 16 + (lane & 15);
    *reinterpret_cast<f32x4*>(sp + (long)qh * SS + scol) = acc[n];
  }
}
template<int MF, int KC>
__global__ __launch_bounds__(256) void gemm_abnat(
    const __bf16* __restrict__ A, long aBatch, int aStride,
    const float* __restrict__ Bn, long bBatch,
    float* __restrict__ Cp, long cBatch, int N)
{
  gemm_abnat_body<MF, KC>(blockIdx.x, blockIdx.y, blockIdx.z, A, aBatch, aStride, Bn, bBatch, Cp, cBatch, N);
}
__global__ __launch_bounds__(256) void k_softmax(const float* __restrict__ Sp, __bf16* __restrict__ attn){
  int qh = blockIdx.x, b = blockIdx.y;
  __bf16* arow = attn + ((long)b * 80 + qh) * SS;
  if (qh >= QH){
    #pragma unroll
    for (int it = 0; it < 16; it++) arow[threadIdx.x + 256 * it] = (__bf16)0.f;
    return;
  }
  const float* r0 = Sp + ((long)b * 80 + qh) * SS;
  const long ys = (long)4 * 80 * SS;
  float x[16]; float mx = -1e30f;
  #pragma unroll
  for (int it = 0; it < 16; it++){
    int s = threadIdx.x + 256 * it;
    x[it] = (r0[s] + r0[s + ys]) + (r0[s + 2 * ys] + r0[s + 3 * ys]);
    mx = fmaxf(mx, x[it]);
  }
  __shared__ float sb[8];
  #pragma unroll
  for (int o = 32; o > 0; o >>= 1) mx = fmaxf(mx, __shfl_xor(mx, o));
  int wid = threadIdx.x >> 6, lane = threadIdx.x & 63;
  if (lane == 0) sb[wid] = mx;
  __syncthreads();
  mx = fmaxf(fmaxf(sb[0], sb[1]), fmaxf(sb[2], sb[3]));
  float sum = 0.f;
  #pragma unroll
  for (int it = 0; it < 16; it++){ x[it] = expf(x[it] - mx); sum += x[it]; }
  #pragma unroll
  for (int o = 32; o > 0; o >>= 1) sum += __shfl_xor(sum, o);
  if (lane == 0) sb[4 + wid] = sum;
  __syncthreads();
  sum = sb[4] + sb[5] + sb[6] + sb[7];
  float inv = 1.f / sum;
  #pragma unroll
  for (int it = 0; it < 16; it++) arow[threadIdx.x + 256 * it] = (__bf16)(x[it] * inv);
}

// ======== cooperative kernel A: prep_qA -> qGEMM -> mkQ2 -> qkGEMM -> mkqk ========
struct PA {
  const float* queries; const float* Wq; const float* Wk;
  __bf16* qA; float* q_p; __bf16* Q2; float* qk_p; __bf16* qk_bf;
};
__global__ __launch_bounds__(256, 2) void k_coopA(PA p){
  cg::grid_group g = cg::this_grid();
  const int bid = blockIdx.x, tid = threadIdx.x;
  // P0: qA = bf16(pad(queries))   32*2048
  { int i = bid * 256 + tid;
    if (i < 32 * 2048){ int r = i >> 11; p.qA[i] = (__bf16)((r < NQQ) ? p.queries[i] : 0.f); } }
  g.sync();
  // P1: q_p[y] = qA @ Wq^T   grid (32,16)
  gemm_bt_body<2, 4, false>(bid & 31, bid >> 5, false, p.qA, 2048, p.Wq, p.q_p, p.Wq, p.q_p, 2048);
  g.sync();
  // P2: Q2 = mask/scale(sum q_p)   80*2048
  for (int j = tid; j < 320; j += 256){
    int i = bid * 320 + j;
    int qh = i >> 11, e = i & 2047;
    float v = 0.f;
    if (qh < QH){
      int h = qh / NQQ, qq = qh - h * NQQ;
      if ((e >> 9) == h){
        float s = 0.f;
        #pragma unroll
        for (int y = 0; y < 16; y++) s += p.q_p[(long)y * 32 * 2048 + qq * 2048 + e];
        v = s * SCALE_F;
      }
    }
    p.Q2[i] = (__bf16)v;
  }
  g.sync();
  // P3: qk_p[y] = Q2 @ Wk   grid (32,16)
  gemm_abnat_body<5, 4>(bid & 31, bid >> 5, 0, p.Q2, 0, 2048, p.Wk, 0, p.qk_p, 0, 2048);
  g.sync();
  // P4: qk_bf = bf16(sum qk_p)
  for (int j = tid; j < 320; j += 256){
    int i = bid * 320 + j;
    float s = 0.f;
    #pragma unroll
    for (int y = 0; y < 16; y++) s += p.qk_p[(long)y * 80 * 2048 + i];
    p.qk_bf[i] = (__bf16)s;
  }
}

// ======== cooperative kernel B: pack_wv ... entries (10 phases) ========
struct PB {
  const float* hs; const float* buf_ent; const float* buf_pri;
  const float* Wv; const float* Wo; const float* ln_w;
  const float* Wgate; const float* Wup; const float* Wdown;
  const float* Wp; const float* bp; const float* Wh; const float* bh;
  const float* V1; const float* b1; const float* V2; const float* b2;
  const float* V3; const float* b3;
  const float* w_p; __bf16* Apack; float* outB_p; __bf16* outB;
  float* ext_p; float* extracted; __bf16* xnb; __bf16* vi;
  float* gate_p; float* up_p; __bf16* hb; float* h1_p; __bf16* h1s;
  float* ffn_p; float* h2_p; float* out;
};
__global__ __launch_bounds__(256, 2) void k_coopB(PB p){
  cg::grid_group g = cg::this_grid();
  const int bid = blockIdx.x, tid = threadIdx.x;
  __shared__ float sb[8];
  __shared__ int tws;
  // P8: Apack = bf16(sum_y w_p)   w_p [b][8][80][2048]; Apack [h][80][2048]
  for (int j = tid; j < 1280; j += 256){
    long i = (long)bid * 1280 + j;                 // 4*80*2048
    int h = (int)(i / (80 * 2048));
    int r = (int)((i / 2048) % 80);
    int e = (int)(i & 2047);
    float v = 0.f;
    if (r < QH){
      int b = r / NQQ, qq = r - b * NQQ;
      const float* base = p.w_p + ((long)b * 8 * 80 + (h * NQQ + qq)) * 2048 + e;
      #pragma unroll
      for (int y = 0; y < 8; y++) v += base[(long)y * 80 * 2048];
    }
    p.Apack[i] = (__bf16)v;
  }
  g.sync();
  // P9: outB_p[y] = Apack(head) @ Wv^T   grid (32,16), HSEL
  gemm_bt_body<5, 4, true>(bid & 31, bid >> 5, false, p.Apack, 2048, p.Wv, p.outB_p, p.Wv, p.outB_p, 2048);
  g.sync();
  // P10: outB = bf16(sum outB_p)
  for (int j = tid; j < 320; j += 256){
    int i = bid * 320 + j;
    float s = 0.f;
    #pragma unroll
    for (int y = 0; y < 16; y++) s += p.outB_p[(long)y * 80 * 2048 + i];
    p.outB[i] = (__bf16)s;
  }
  g.sync();
  // P11: ext_p[y] = outB @ Wo^T   grid (32,16)
  gemm_bt_body<5, 4, false>(bid & 31, bid >> 5, false, p.outB, 2048, p.Wo, p.ext_p, p.Wo, p.ext_p, 2048);
  g.sync();
  // P12: rms + extracted + vi
  { int r = bid;
    if (r >= 80 && r < 96){
      if (r < 84){                                 // vi[b][2048..4096] = hs[b, S-1, :]
        int b = r - 80;
        const float* src = p.hs + ((long)b * SS + (SS - 1)) * HH;
        #pragma unroll
        for (int it = 0; it < 8; it++){
          int e = tid + 256 * it;
          p.vi[(long)b * 4096 + 2048 + e] = (__bf16)src[e];
        }
      } else {                                     // zero vi rows 4..15
        int row = 4 + (r - 84);
        #pragma unroll
        for (int it = 0; it < 16; it++)
          p.vi[(long)row * 4096 + tid + 256 * it] = (__bf16)0.f;
      }
    } else if (r < 80){
      float xv[8]; float ss = 0.f;
      #pragma unroll
      for (int it = 0; it < 8; it++){
        int e = tid + 256 * it;
        float s = 0.f;
        #pragma unroll
        for (int y = 0; y < 16; y++) s += p.ext_p[((long)y * 80 + r) * 2048 + e];
        p.extracted[(long)r * 2048 + e] = s;
        xv[it] = s;
        ss += s * s;
      }
      if (r < QH){
        int b = r / NQQ, qq = r - b * NQQ;
        if (qq < 16){
          ss = block_sum(ss, sb);
          float inv = 1.f / sqrtf(ss * (1.f / 2048.f) + 1e-6f);
          __bf16* dst = p.xnb + (long)(b * 16 + qq) * HH;
          #pragma unroll
          for (int it = 0; it < 8; it++){
            int e = tid + 256 * it;
            dst[e] = (__bf16)(xv[it] * inv * p.ln_w[e]);
          }
        } else if (qq == 17){
          #pragma unroll
          for (int it = 0; it < 8; it++){
            int e = tid + 256 * it;
            p.vi[(long)b * 4096 + e] = (__bf16)xv[it];
          }
        }
      }
    }
  }
  g.sync();
  // P13: gate/up GEMM (256 blocks) + V1 GEMM (256 blocks)
  if (bid < 256){
    int t = bid;   // (64,2,2) KC=32
    gemm_bt_body<4, 32, false>(t & 63, (t >> 6) & 1, (t >> 7) != 0,
                               p.xnb, 2048, p.Wgate, p.gate_p, p.Wup, p.up_p, 4096);
  } else {
    int t = bid - 256;   // (32,8) KC=16
    gemm_bt_body<1, 16, false>(t & 31, t >> 5, false, p.vi, 4096, p.V1, p.h1_p, p.V1, p.h1_p, 2048);
  }
  g.sync();
  // P14: act (all blocks) + h1act (blocks <128)
  for (int j = tid; j < 512; j += 256){
    long i = (long)bid * 512 + j;                  // 64*4096
    float gv = p.gate_p[i] + p.gate_p[(long)64 * 4096 + i];
    float uv = p.up_p[i]   + p.up_p[(long)64 * 4096 + i];
    p.hb[i] = (__bf16)(siluf(gv) * uv);
  }
  if (bid < 128){
    int i = bid * 256 + tid;                       // 16*2048
    int r = i >> 11, e = i & 2047;
    float v = 0.f;
    if (r < 4){
      float s = 0.f;
      #pragma unroll
      for (int y = 0; y < 8; y++) s += p.h1_p[(long)y * 16 * 2048 + i];
      v = siluf(s + p.b1[e]);
    }
    p.h1s[i] = (__bf16)v;
  }
  g.sync();
  // P15: down GEMM (256 blocks) + V2 GEMM (128 blocks)
  if (bid < 256){
    int t = bid;   // (32,8) KC=16
    gemm_bt_body<4, 16, false>(t & 31, t >> 5, false, p.hb, 4096, p.Wdown, p.ffn_p, p.Wdown, p.ffn_p, 2048);
  } else if (bid < 384){
    int t = bid - 256;   // (8,16) KC=4
    gemm_bt_body<1, 4, false>(t & 7, t >> 3, false, p.h1s, 2048, p.V2, p.h2_p, p.V2, p.h2_p, 512);
  }
  g.sync();
  // P16: epilogue — memory+priority / confidence / value
  { int blk = bid;
    if (blk < 64){
      int b = blk >> 4, qq = blk & 15;
      const float* ext = p.extracted + (long)(b * NQQ + qq) * HH;
      float pv = 0.f;
      #pragma unroll
      for (int it = 0; it < 8; it++){
        int e = tid + 256 * it;
        float f = 0.f;
        #pragma unroll
        for (int y = 0; y < 8; y++) f += p.ffn_p[((long)y * 64 + blk) * 2048 + e];
        float m = ext[e] + f;
        p.out[OUT_MEM + (long)blk * 2048 + e] = m;
        pv += m * p.Wp[e];
      }
      pv = block_sum(pv, sb);
      if (tid == 0) p.out[OUT_PRI + blk] = 1.f / (1.f + expf(-(pv + p.bp[0])));
    } else if (blk < 68){
      int b = blk - 64;
      const float* m = p.extracted + (long)(b * NQQ + 16) * HH;
      float v = 0.f;
      #pragma unroll
      for (int it = 0; it < 8; it++){ int e = tid + 256 * it; v += m[e] * p.Wh[e]; }
      v = block_sum(v, sb);
      if (tid == 0) p.out[OUT_CONF + b] = 1.f / (1.f + expf(-(v + p.bh[0])));
    } else if (blk < 72){
      int b = blk - 68;
      float v = 0.f;
      #pragma unroll
      for (int it = 0; it < 2; it++){
        int j = tid + 256 * it;
        float s = 0.f;
        #pragma unroll
        for (int y = 0; y < 16; y++) s += p.h2_p[(long)y * 16 * 512 + b * 512 + j];
        v += siluf(s + p.b2[j]) * p.V3[j];
      }
      v = block_sum(v, sb);
      if (tid == 0) p.out[OUT_VAL + b] = v + p.b3[0];
    }
  }
  g.sync();
  // P17: scan (block-redundant) + entry copy.  blocks 0..127
  if (bid < 128){
    if (tid < 64){
      int lane = tid;
      float pr0 = p.buf_pri[lane], pr1 = p.buf_pri[lane + 64];
      int tw0 = -1, tw1 = -1;
      for (int i = 0; i < 16; i++){
        float pp = p.out[OUT_PRI + i];
        float v; int idx;
        if (pr0 <= pr1){ v = pr0; idx = lane; } else { v = pr1; idx = lane + 64; }
        #pragma unroll
        for (int o = 32; o > 0; o >>= 1){
          float ov = __shfl_xor(v, o);
          int   oi = __shfl_xor(idx, o);
          if (ov < v || (ov == v && oi < idx)){ v = ov; idx = oi; }
        }
        if (pp > v){
          if (idx == lane)          { pr0 = pp; tw0 = i; }
          else if (idx == lane + 64){ pr1 = pp; tw1 = i; }
        }
      }
      if (bid == 0){
        p.out[OUT_NEWPRI + lane]      = pr0;
        p.out[OUT_NEWPRI + lane + 64] = pr1;
      }
      if (lane == (bid & 63)) tws = (bid < 64) ? tw0 : tw1;
    }
    __syncthreads();
    int t = tws;
    const f32x4* s = reinterpret_cast<const f32x4*>(
        (t < 0) ? (p.buf_ent + (long)bid * HH) : (p.out + OUT_MEM + (long)t * HH));
    f32x4* d = reinterpret_cast<f32x4*>(p.out + OUT_ENT + (long)bid * HH);
    #pragma unroll
    for (int i = 0; i < 2; i++) d[tid + 256 * i] = s[tid + 256 * i];
  }
}

// ---------------- launcher ----------------
extern "C" void kernel_launch(void* const* d_in, const int* in_sizes, int n_in,
                              void* d_out, int out_size, void* d_ws, size_t ws_size,
                              hipStream_t stream)
{
  const float* hs      = (const float*)d_in[0];
  const float* buf_ent = (const float*)d_in[1];
  const float* buf_pri = (const float*)d_in[2];
  const float* queries = (const float*)d_in[3];
  const float* Wq  = (const float*)d_in[4];
  const float* Wk  = (const float*)d_in[5];
  const float* Wv  = (const float*)d_in[6];
  const float* Wo  = (const float*)d_in[7];
  const float* ln_w= (const float*)d_in[8];
  const float* Wgate=(const float*)d_in[9];
  const float* Wup = (const float*)d_in[10];
  const float* Wdown=(const float*)d_in[11];
  const float* Wp  = (const float*)d_in[12];
  const float* bp  = (const float*)d_in[13];
  const float* Wh  = (const float*)d_in[14];
  const float* bh  = (const float*)d_in[15];
  const float* V1  = (const float*)d_in[16];
  const float* b1  = (const float*)d_in[17];
  const float* V2  = (const float*)d_in[18];
  const float* b2  = (const float*)d_in[19];
  const float* V3  = (const float*)d_in[20];
  const float* b3  = (const float*)d_in[21];
  float* out = (float*)d_out;
  char* ws = (char*)d_ws;

  // ---- RegionA (20 MB, time-aliased; no memset, no atomics) ----
  float* q_p      = (float*)(ws + 0);            // [16][32][2048]
  float* qk_p     = (float*)(ws + 0);            // [16][80][2048]
  float* scores_p = (float*)(ws + 0);            // [4][4][80][4096]
  float* w_p      = (float*)(ws + 0);            // [4][8][80][2048]
  float* outB_p   = (float*)(ws + 0);            // [16][80][2048]
  float* ext_p    = (float*)(ws + 0);            // [16][80][2048]
  float* gate_p   = (float*)(ws + 0);            // [2][64][4096]
  float* up_p     = (float*)(ws + 2097152);      // [2][64][4096]
  float* ffn_p    = (float*)(ws + 0);            // [8][64][2048]
  // ---- persistents ----
  __bf16* qA    = (__bf16*)(ws + 20971520);      // 32*2048
  __bf16* Q2    = (__bf16*)(ws + 21102592);      // 80*2048
  __bf16* qk_bf = (__bf16*)(ws + 21430272);      // 80*2048
  __bf16* attn  = (__bf16*)(ws + 21757952);      // 4*80*4096
  __bf16* Apack = (__bf16*)(ws + 24379392);      // 4*80*2048
  __bf16* outB  = (__bf16*)(ws + 25690112);      // 80*2048
  float*  extracted = (float*)(ws + 26017792);   // 80*2048 f32
  __bf16* xnb   = (__bf16*)(ws + 26673152);      // 64*2048
  __bf16* hb    = (__bf16*)(ws + 26935296);      // 64*4096
  __bf16* vi    = (__bf16*)(ws + 27459584);      // 16*4096
  __bf16* h1s   = (__bf16*)(ws + 27590656);      // 16*2048
  float*  h1_p  = (float*)(ws + 27656192);       // [8][16][2048]
  float*  h2_p  = (float*)(ws + 29753344);       // [16][16][512]

  // --- launch 1: cooperative q/qk chain ---
  PA pa{queries, Wq, Wk, qA, q_p, Q2, qk_p, qk_bf};
  void* argsA[] = {&pa};
  hipLaunchCooperativeKernel(reinterpret_cast<void*>(k_coopA),
                             dim3(512), dim3(256), argsA, 0, stream);
  // --- launch 2: pass1 scores ---
  gemm_pass1<16><<<dim3(64, 4, 4), 256, 0, stream>>>(hs, qk_bf, scores_p);
  // --- launch 3: softmax ---
  k_softmax<<<dim3(80, 4), 256, 0, stream>>>(scores_p, attn);
  // --- launch 4: pass3 weighted ---
  gemm_abnat<5, 16><<<dim3(32, 8, 4), 256, 0, stream>>>(attn, 80L * 4096, 4096,
      hs, (long)SS * HH, w_p, 8L * 80 * 2048, 2048);
  // --- launch 5: cooperative tail ---
  PB pb{hs, buf_ent, buf_pri, Wv, Wo, ln_w, Wgate, Wup, Wdown,
        Wp, bp, Wh, bh, V1, b1, V2, b2, V3, b3,
        w_p, Apack, outB_p, outB, ext_p, extracted, xnb, vi,
        gate_p, up_p, hb, h1_p, h1s, ffn_p, h2_p, out};
  void* argsB[] = {&pb};
  hipLaunchCooperativeKernel(reinterpret_cast<void*>(k_coopB),
                             dim3(512), dim3(256), argsB, 0, stream);
}

// Round 6
// 254.586 us; speedup vs baseline: 3.9615x; 3.9615x over previous
//
#include <hip/hip_runtime.h>

// ---------------- constants ----------------
#define SS    4096
#define HH    2048
#define NQQ   18
#define QH    72
#define SCALE_F 0.044194173824159216f   // 1/sqrt(512)

// output regions (f32 elements)
#define OUT_MEM     0
#define OUT_PRI     131072
#define OUT_CONF    131136
#define OUT_VAL     131140
#define OUT_ENT     131144
#define OUT_NEWPRI  393288

typedef float  f32x4  __attribute__((ext_vector_type(4)));
typedef __bf16 bf16x8 __attribute__((ext_vector_type(8)));

#define DEVFN static __device__ __forceinline__

DEVFN bf16x8 pack8(f32x4 lo, f32x4 hi){
  bf16x8 r;
  #pragma unroll
  for (int i = 0; i < 4; i++){ r[i] = (__bf16)lo[i]; r[i+4] = (__bf16)hi[i]; }
  return r;
}
DEVFN float siluf(float x){ return x / (1.f + expf(-x)); }
DEVFN float block_sum(float v, float* sb){   // 256 threads
  #pragma unroll
  for (int o = 32; o > 0; o >>= 1) v += __shfl_xor(v, o);
  int wid = threadIdx.x >> 6, lane = threadIdx.x & 63;
  if (lane == 0) sb[wid] = v;
  __syncthreads();
  v = sb[0] + sb[1] + sb[2] + sb[3];
  __syncthreads();
  return v;
}

// ======== GEMM-BT body: Cp[y][Mp][N] = A_bf16(Mp,Kf) @ B_f32(N,Kf)^T ========
template<int MF, int KC, bool HSEL>
DEVFN void gemm_bt_body(int bx, int by, bool zsel,
    const __bf16* __restrict__ A, int Kf,
    const float* __restrict__ B0, float* __restrict__ C0,
    const float* __restrict__ B1, float* __restrict__ C1,
    int N)
{
  constexpr int Mp = 16 * MF;
  const int lane = threadIdx.x & 63, w = threadIdx.x >> 6;
  const int n0 = bx * 64 + w * 16;
  const int k0 = by * KC * 32;
  const float* B = zsel ? B1 : B0;
  float* Cp      = zsel ? C1 : C0;
  const __bf16* aBase = A + (HSEL ? (long)(n0 >> 9) * Mp * Kf : 0)
                          + (long)(lane & 15) * Kf + k0 + 8 * (lane >> 4);
  const float* bBase = B + (long)(n0 + (lane & 15)) * Kf + k0 + 8 * (lane >> 4);
  f32x4 acc[MF];
  #pragma unroll
  for (int m = 0; m < MF; m++) acc[m] = (f32x4)(0.f);
  #pragma unroll 4
  for (int c = 0; c < KC; c++){
    f32x4 lo = *reinterpret_cast<const f32x4*>(bBase + c * 32);
    f32x4 hi = *reinterpret_cast<const f32x4*>(bBase + c * 32 + 4);
    bf16x8 bb = pack8(lo, hi);
    #pragma unroll
    for (int m = 0; m < MF; m++){
      bf16x8 aa = *reinterpret_cast<const bf16x8*>(aBase + (long)m * 16 * Kf + c * 32);
      acc[m] = __builtin_amdgcn_mfma_f32_16x16x32_bf16(aa, bb, acc[m], 0, 0, 0);
    }
  }
  float* cp = Cp + (long)by * Mp * N;
  int row0 = 4 * (lane >> 4), col = n0 + (lane & 15);
  #pragma unroll
  for (int m = 0; m < MF; m++)
    #pragma unroll
    for (int r = 0; r < 4; r++)
      cp[(long)(m * 16 + row0 + r) * N + col] = acc[m][r];
}
template<int MF, int KC, bool HSEL>
__global__ __launch_bounds__(256) void gemm_bt(
    const __bf16* __restrict__ A, int Kf,
    const float* __restrict__ B0, float* __restrict__ C0,
    const float* __restrict__ B1, float* __restrict__ C1, int N)
{
  gemm_bt_body<MF, KC, HSEL>(blockIdx.x, blockIdx.y, blockIdx.z != 0, A, Kf, B0, C0, B1, C1, N);
}

// ======== GEMM-ABNAT: Cp[z][y][Mp][N] = A_bf16(z)(Mp,aStride) @ Bn_f32(z)(K,N) ========
template<int MF, int KC>
__global__ __launch_bounds__(256) void gemm_abnat(
    const __bf16* __restrict__ A, long aBatch, int aStride,
    const float* __restrict__ Bn, long bBatch,
    float* __restrict__ Cp, long cBatch,
    int N)
{
  constexpr int Mp = 16 * MF;
  const int lane = threadIdx.x & 63, w = threadIdx.x >> 6;
  const int z = blockIdx.z;
  const int n0 = blockIdx.x * 64 + w * 16;
  const int k0 = blockIdx.y * KC * 32;
  const __bf16* aBase = A + z * aBatch + (long)(lane & 15) * aStride + k0 + 8 * (lane >> 4);
  const float* bBase = Bn + z * bBatch + (long)(k0 + 8 * (lane >> 4)) * N + n0 + (lane & 15);
  f32x4 acc[MF];
  #pragma unroll
  for (int m = 0; m < MF; m++) acc[m] = (f32x4)(0.f);
  #pragma unroll 2
  for (int c = 0; c < KC; c++){
    const float* bp = bBase + (long)c * 32 * N;
    bf16x8 bb;
    #pragma unroll
    for (int j = 0; j < 8; j++) bb[j] = (__bf16)bp[(long)j * N];
    #pragma unroll
    for (int m = 0; m < MF; m++){
      bf16x8 aa = *reinterpret_cast<const bf16x8*>(aBase + (long)m * 16 * aStride + c * 32);
      acc[m] = __builtin_amdgcn_mfma_f32_16x16x32_bf16(aa, bb, acc[m], 0, 0, 0);
    }
  }
  float* cp = Cp + z * cBatch + (long)blockIdx.y * Mp * N;
  int row0 = 4 * (lane >> 4), col = n0 + (lane & 15);
  #pragma unroll
  for (int m = 0; m < MF; m++)
    #pragma unroll
    for (int r = 0; r < 4; r++)
      cp[(long)(m * 16 + row0 + r) * N + col] = acc[m][r];
}

// ======== q GEMM with f32 A (queries), row-pad + scale folded in ========
// Cp[y][32][2048] = bf16(SCALE * pad32(queries)) @ Wq^T.  grid (32,16), KC=4.
__global__ __launch_bounds__(256) void gemm_qA(
    const float* __restrict__ queries, const float* __restrict__ Wq, float* __restrict__ Cp)
{
  const int lane = threadIdx.x & 63, w = threadIdx.x >> 6;
  const int n0 = blockIdx.x * 64 + w * 16;
  const int k0 = blockIdx.y * 4 * 32;
  const int r0 = lane & 15, r1 = r0 + 16;
  const float f1 = (r1 < NQQ) ? SCALE_F : 0.f;
  const float* a0 = queries + (long)r0 * HH + k0 + 8 * (lane >> 4);
  const float* a1 = queries + (long)((r1 < NQQ) ? r1 : 0) * HH + k0 + 8 * (lane >> 4);
  const float* bBase = Wq + (long)(n0 + r0) * HH + k0 + 8 * (lane >> 4);
  f32x4 acc[2]; acc[0] = (f32x4)(0.f); acc[1] = (f32x4)(0.f);
  #pragma unroll
  for (int c = 0; c < 4; c++){
    f32x4 blo = *reinterpret_cast<const f32x4*>(bBase + c * 32);
    f32x4 bhi = *reinterpret_cast<const f32x4*>(bBase + c * 32 + 4);
    bf16x8 bb = pack8(blo, bhi);
    f32x4 l0 = *reinterpret_cast<const f32x4*>(a0 + c * 32);
    f32x4 h0 = *reinterpret_cast<const f32x4*>(a0 + c * 32 + 4);
    f32x4 l1 = *reinterpret_cast<const f32x4*>(a1 + c * 32);
    f32x4 h1 = *reinterpret_cast<const f32x4*>(a1 + c * 32 + 4);
    bf16x8 aa0, aa1;
    #pragma unroll
    for (int i = 0; i < 4; i++){
      aa0[i] = (__bf16)(l0[i] * SCALE_F); aa0[i+4] = (__bf16)(h0[i] * SCALE_F);
      aa1[i] = (__bf16)(l1[i] * f1);      aa1[i+4] = (__bf16)(h1[i] * f1);
    }
    acc[0] = __builtin_amdgcn_mfma_f32_16x16x32_bf16(aa0, bb, acc[0], 0, 0, 0);
    acc[1] = __builtin_amdgcn_mfma_f32_16x16x32_bf16(aa1, bb, acc[1], 0, 0, 0);
  }
  float* cp = Cp + (long)blockIdx.y * 32 * HH;
  int row0 = 4 * (lane >> 4), col = n0 + r0;
  #pragma unroll
  for (int m = 0; m < 2; m++)
    #pragma unroll
    for (int r = 0; r < 4; r++)
      cp[(long)(m * 16 + row0 + r) * HH + col] = acc[m][r];
}

// ======== pass1: Sp[y][b][qh][s] = hs(b)(s,H) @ qk_bf16(80,H)^T, transposed store ========
template<int KC>
__global__ __launch_bounds__(256) void gemm_pass1(
    const float* __restrict__ hs, const __bf16* __restrict__ qk,
    float* __restrict__ Sp)
{
  const int lane = threadIdx.x & 63, w = threadIdx.x >> 6;
  const int b = blockIdx.z;
  const int s0 = blockIdx.x * 64 + w * 16;
  const int k0 = blockIdx.y * KC * 32;
  const float* aBase = hs + ((long)b * SS + s0 + (lane & 15)) * HH + k0 + 8 * (lane >> 4);
  const __bf16* bBase = qk + (long)(lane & 15) * HH + k0 + 8 * (lane >> 4);
  f32x4 acc[5];
  #pragma unroll
  for (int n = 0; n < 5; n++) acc[n] = (f32x4)(0.f);
  #pragma unroll 4
  for (int c = 0; c < KC; c++){
    f32x4 lo = *reinterpret_cast<const f32x4*>(aBase + c * 32);
    f32x4 hi = *reinterpret_cast<const f32x4*>(aBase + c * 32 + 4);
    bf16x8 aa = pack8(lo, hi);
    #pragma unroll
    for (int n = 0; n < 5; n++){
      bf16x8 bb = *reinterpret_cast<const bf16x8*>(bBase + (long)n * 16 * HH + c * 32);
      acc[n] = __builtin_amdgcn_mfma_f32_16x16x32_bf16(aa, bb, acc[n], 0, 0, 0);
    }
  }
  float* sp = Sp + ((long)blockIdx.y * 4 + b) * 80 * SS;
  int scol = s0 + 4 * (lane >> 4);
  #pragma unroll
  for (int n = 0; n < 5; n++){
    int qh = n * 16 + (lane & 15);
    *reinterpret_cast<f32x4*>(sp + (long)qh * SS + scol) = acc[n];
  }
}

// ======== merged FFN launches (no grid sync; independent GEMMs by block range) ========
__global__ __launch_bounds__(256) void k_ffn1(
    const __bf16* __restrict__ xnb, const float* __restrict__ Wgate, const float* __restrict__ Wup,
    float* __restrict__ gate_p, float* __restrict__ up_p,
    const __bf16* __restrict__ vi, const float* __restrict__ V1, float* __restrict__ h1_p)
{
  int bid = blockIdx.x;
  if (bid < 1024){                                   // gate/up: (64,8,2), KC=8, 8 slabs
    int z = bid >> 9, rem = bid & 511;
    gemm_bt_body<4, 8, false>(rem & 63, rem >> 6, z != 0, xnb, 2048, Wgate, gate_p, Wup, up_p, 4096);
  } else {                                           // V1: (32,16), KC=8, 16 slabs
    int t = bid - 1024;
    gemm_bt_body<1, 8, false>(t & 31, t >> 5, false, vi, 4096, V1, h1_p, V1, h1_p, 2048);
  }
}
__global__ __launch_bounds__(256) void k_ffn2(
    const __bf16* __restrict__ hb, const float* __restrict__ Wdown, float* __restrict__ ffn_p,
    const __bf16* __restrict__ h1s, const float* __restrict__ V2, float* __restrict__ h2_p)
{
  int bid = blockIdx.x;
  if (bid < 512){                                    // down: (32,16), KC=8, 16 slabs
    gemm_bt_body<4, 8, false>(bid & 31, bid >> 5, false, hb, 4096, Wdown, ffn_p, Wdown, ffn_p, 2048);
  } else {                                           // V2: (8,16), KC=4, 16 slabs
    int t = bid - 512;
    gemm_bt_body<1, 4, false>(t & 7, t >> 3, false, h1s, 2048, V2, h2_p, V2, h2_p, 512);
  }
}
__global__ void k_act2(const float* __restrict__ gate_p, const float* __restrict__ up_p,
                       __bf16* __restrict__ hb,
                       const float* __restrict__ h1_p, const float* __restrict__ b1,
                       __bf16* __restrict__ h1s)
{
  int bid = blockIdx.x;
  if (bid < 1024){                                   // silu(gate)*up, 8 slabs
    long i = (long)bid * 256 + threadIdx.x;          // 64*4096
    float g = 0.f, u = 0.f;
    #pragma unroll
    for (int y = 0; y < 8; y++){
      g += gate_p[(long)y * 64 * 4096 + i];
      u += up_p[(long)y * 64 * 4096 + i];
    }
    hb[i] = (__bf16)(siluf(g) * u);
  } else {                                           // h1act, 16 slabs
    int i = (bid - 1024) * 256 + threadIdx.x;        // 16*2048
    int r = i >> 11, e = i & 2047;
    float v = 0.f;
    if (r < 4){
      float s = 0.f;
      #pragma unroll
      for (int y = 0; y < 16; y++) s += h1_p[(long)y * 16 * 2048 + i];
      v = siluf(s + b1[e]);
    }
    h1s[i] = (__bf16)v;
  }
}

// ---------------- small / epilogue kernels ----------------
__global__ void k_mkQ2(const float* __restrict__ q_p, __bf16* __restrict__ Q2){
  int i = blockIdx.x * 256 + threadIdx.x;       // 80*2048
  int qh = i >> 11, e = i & 2047;
  float v = 0.f;
  if (qh < QH){
    int h = qh / NQQ, qq = qh - h * NQQ;
    if ((e >> 9) == h){
      float s = 0.f;
      #pragma unroll
      for (int y = 0; y < 16; y++) s += q_p[(long)y * 32 * 2048 + qq * 2048 + e];
      v = s;                                     // scale already folded into gemm_qA
    }
  }
  Q2[i] = (__bf16)v;
}
__global__ void k_mkqk(const float* __restrict__ qk_p, __bf16* __restrict__ qk_bf){
  int i = blockIdx.x * 256 + threadIdx.x;       // 80*2048
  float s = 0.f;
  #pragma unroll
  for (int y = 0; y < 16; y++) s += qk_p[(long)y * 80 * 2048 + i];
  qk_bf[i] = (__bf16)s;
}
__global__ __launch_bounds__(256) void k_softmax(const float* __restrict__ Sp, __bf16* __restrict__ attn){
  int qh = blockIdx.x, b = blockIdx.y;
  __bf16* arow = attn + ((long)b * 80 + qh) * SS;
  if (qh >= QH){
    #pragma unroll
    for (int it = 0; it < 16; it++) arow[threadIdx.x + 256 * it] = (__bf16)0.f;
    return;
  }
  const float* r0 = Sp + ((long)b * 80 + qh) * SS;
  const long ys = (long)4 * 80 * SS;
  float x[16]; float mx = -1e30f;
  #pragma unroll
  for (int it = 0; it < 16; it++){
    int s = threadIdx.x + 256 * it;
    x[it] = (r0[s] + r0[s + ys]) + (r0[s + 2 * ys] + r0[s + 3 * ys]);
    mx = fmaxf(mx, x[it]);
  }
  __shared__ float sb[8];
  #pragma unroll
  for (int o = 32; o > 0; o >>= 1) mx = fmaxf(mx, __shfl_xor(mx, o));
  int wid = threadIdx.x >> 6, lane = threadIdx.x & 63;
  if (lane == 0) sb[wid] = mx;
  __syncthreads();
  mx = fmaxf(fmaxf(sb[0], sb[1]), fmaxf(sb[2], sb[3]));
  float sum = 0.f;
  #pragma unroll
  for (int it = 0; it < 16; it++){ x[it] = expf(x[it] - mx); sum += x[it]; }
  #pragma unroll
  for (int o = 32; o > 0; o >>= 1) sum += __shfl_xor(sum, o);
  if (lane == 0) sb[4 + wid] = sum;
  __syncthreads();
  sum = sb[4] + sb[5] + sb[6] + sb[7];
  float inv = 1.f / sum;
  #pragma unroll
  for (int it = 0; it < 16; it++) arow[threadIdx.x + 256 * it] = (__bf16)(x[it] * inv);
}
// w_p layout [b][y][80][2048], y in [0,8)
__global__ void k_pack_wv(const float* __restrict__ w_p, __bf16* __restrict__ Apack){
  int i = blockIdx.x * 256 + threadIdx.x;       // 4*80*2048
  int h = i / (80 * 2048);
  int r = (i / 2048) % 80;
  int e = i & 2047;
  float v = 0.f;
  if (r < QH){
    int b = r / NQQ, qq = r - b * NQQ;
    const float* base = w_p + ((long)b * 8 * 80 + (h * NQQ + qq)) * 2048 + e;
    #pragma unroll
    for (int y = 0; y < 8; y++) v += base[(long)y * 80 * 2048];
  }
  Apack[i] = (__bf16)v;
}
__global__ void k_sum_outB(const float* __restrict__ outB_p, __bf16* __restrict__ outB){
  int i = blockIdx.x * 256 + threadIdx.x;       // 80*2048
  float s = 0.f;
  #pragma unroll
  for (int y = 0; y < 16; y++) s += outB_p[(long)y * 80 * 2048 + i];
  outB[i] = (__bf16)s;
}
// rms + extracted materialization + vi packing fused. grid 96.
__global__ __launch_bounds__(256) void k_rms(const float* __restrict__ ext_p, const float* __restrict__ ln_w,
                                             const float* __restrict__ hs,
                                             float* __restrict__ extracted, __bf16* __restrict__ xnb,
                                             __bf16* __restrict__ vi){
  int r = blockIdx.x;
  if (r >= 80){
    if (r < 84){                                 // vi[b][2048..4096] = hs[b, S-1, :]
      int b = r - 80;
      const float* src = hs + ((long)b * SS + (SS - 1)) * HH;
      #pragma unroll
      for (int it = 0; it < 8; it++){
        int e = threadIdx.x + 256 * it;
        vi[(long)b * 4096 + 2048 + e] = (__bf16)src[e];
      }
    } else {                                     // zero vi rows 4..15
      int row = 4 + (r - 84);
      #pragma unroll
      for (int it = 0; it < 16; it++)
        vi[(long)row * 4096 + threadIdx.x + 256 * it] = (__bf16)0.f;
    }
    return;
  }
  float xv[8]; float ss = 0.f;
  #pragma unroll
  for (int it = 0; it < 8; it++){
    int e = threadIdx.x + 256 * it;
    float s = 0.f;
    #pragma unroll
    for (int y = 0; y < 16; y++) s += ext_p[((long)y * 80 + r) * 2048 + e];
    extracted[(long)r * 2048 + e] = s;
    xv[it] = s;
    ss += s * s;
  }
  if (r >= QH) return;
  int b = r / NQQ, qq = r - b * NQQ;
  if (qq < 16){
    __shared__ float sb[4];
    ss = block_sum(ss, sb);
    float inv = 1.f / sqrtf(ss * (1.f / 2048.f) + 1e-6f);
    __bf16* dst = xnb + (long)(b * 16 + qq) * HH;
    #pragma unroll
    for (int it = 0; it < 8; it++){
      int e = threadIdx.x + 256 * it;
      dst[e] = (__bf16)(xv[it] * inv * ln_w[e]);
    }
  } else if (qq == 17){                          // vi[b][0..2048] = extracted row
    #pragma unroll
    for (int it = 0; it < 8; it++){
      int e = threadIdx.x + 256 * it;
      vi[(long)b * 4096 + e] = (__bf16)xv[it];
    }
  }
}
// memory + priority + confidence + value, one kernel. grid 72.
__global__ __launch_bounds__(256) void k_epilogue(
    const float* __restrict__ extracted, const float* __restrict__ ffn_p,
    const float* __restrict__ h2_p,
    const float* __restrict__ Wp, const float* __restrict__ bp,
    const float* __restrict__ Wh, const float* __restrict__ bh,
    const float* __restrict__ b2, const float* __restrict__ V3, const float* __restrict__ b3,
    float* __restrict__ out)
{
  __shared__ float sb[4];
  int blk = blockIdx.x;
  if (blk < 64){                                 // memory row + priority
    int b = blk >> 4, qq = blk & 15;
    const float* ext = extracted + (long)(b * NQQ + qq) * HH;
    float pv = 0.f;
    #pragma unroll
    for (int it = 0; it < 8; it++){
      int e = threadIdx.x + 256 * it;
      float f = 0.f;
      #pragma unroll
      for (int y = 0; y < 16; y++) f += ffn_p[((long)y * 64 + blk) * 2048 + e];
      float m = ext[e] + f;
      out[OUT_MEM + (long)blk * 2048 + e] = m;
      pv += m * Wp[e];
    }
    pv = block_sum(pv, sb);
    if (threadIdx.x == 0) out[OUT_PRI + blk] = 1.f / (1.f + expf(-(pv + bp[0])));
  } else if (blk < 68){                          // confidence
    int b = blk - 64;
    const float* m = extracted + (long)(b * NQQ + 16) * HH;
    float v = 0.f;
    #pragma unroll
    for (int it = 0; it < 8; it++){ int e = threadIdx.x + 256 * it; v += m[e] * Wh[e]; }
    v = block_sum(v, sb);
    if (threadIdx.x == 0) out[OUT_CONF + b] = 1.f / (1.f + expf(-(v + bh[0])));
  } else {                                       // value
    int b = blk - 68;
    float v = 0.f;
    #pragma unroll
    for (int it = 0; it < 2; it++){
      int j = threadIdx.x + 256 * it;
      float s = 0.f;
      #pragma unroll
      for (int y = 0; y < 16; y++) s += h2_p[(long)y * 16 * 512 + b * 512 + j];
      v += siluf(s + b2[j]) * V3[j];
    }
    v = block_sum(v, sb);
    if (threadIdx.x == 0) out[OUT_VAL + b] = v + b3[0];
  }
}
// block-redundant scan + entry copy (no grid sync, 128 blocks)
__global__ void k_scanentries(const float* __restrict__ buf_pri, const float* __restrict__ buf_ent,
                              float* __restrict__ out){
  __shared__ int tws;
  int bid = blockIdx.x, tid = threadIdx.x;
  if (tid < 64){
    int lane = tid;
    float pr0 = buf_pri[lane], pr1 = buf_pri[lane + 64];
    int tw0 = -1, tw1 = -1;
    for (int i = 0; i < 16; i++){
      float pp = out[OUT_PRI + i];
      float v; int idx;
      if (pr0 <= pr1){ v = pr0; idx = lane; } else { v = pr1; idx = lane + 64; }
      #pragma unroll
      for (int o = 32; o > 0; o >>= 1){
        float ov = __shfl_xor(v, o);
        int   oi = __shfl_xor(idx, o);
        if (ov < v || (ov == v && oi < idx)){ v = ov; idx = oi; }
      }
      if (pp > v){
        if (idx == lane)          { pr0 = pp; tw0 = i; }
        else if (idx == lane + 64){ pr1 = pp; tw1 = i; }
      }
    }
    if (bid == 0){
      out[OUT_NEWPRI + lane]      = pr0;
      out[OUT_NEWPRI + lane + 64] = pr1;
    }
    if (lane == (bid & 63)) tws = (bid < 64) ? tw0 : tw1;
  }
  __syncthreads();
  int t = tws;
  const f32x4* s = reinterpret_cast<const f32x4*>(
      (t < 0) ? (buf_ent + (long)bid * HH) : (out + OUT_MEM + (long)t * HH));
  f32x4* d = reinterpret_cast<f32x4*>(out + OUT_ENT + (long)bid * HH);
  #pragma unroll
  for (int i = 0; i < 2; i++) d[tid + 256 * i] = s[tid + 256 * i];
}

// ---------------- launcher ----------------
extern "C" void kernel_launch(void* const* d_in, const int* in_sizes, int n_in,
                              void* d_out, int out_size, void* d_ws, size_t ws_size,
                              hipStream_t stream)
{
  const float* hs      = (const float*)d_in[0];
  const float* buf_ent = (const float*)d_in[1];
  const float* buf_pri = (const float*)d_in[2];
  const float* queries = (const float*)d_in[3];
  const float* Wq  = (const float*)d_in[4];
  const float* Wk  = (const float*)d_in[5];
  const float* Wv  = (const float*)d_in[6];
  const float* Wo  = (const float*)d_in[7];
  const float* ln_w= (const float*)d_in[8];
  const float* Wgate=(const float*)d_in[9];
  const float* Wup = (const float*)d_in[10];
  const float* Wdown=(const float*)d_in[11];
  const float* Wp  = (const float*)d_in[12];
  const float* bp  = (const float*)d_in[13];
  const float* Wh  = (const float*)d_in[14];
  const float* bh  = (const float*)d_in[15];
  const float* V1  = (const float*)d_in[16];
  const float* b1  = (const float*)d_in[17];
  const float* V2  = (const float*)d_in[18];
  const float* b2  = (const float*)d_in[19];
  const float* V3  = (const float*)d_in[20];
  const float* b3  = (const float*)d_in[21];
  float* out = (float*)d_out;
  char* ws = (char*)d_ws;

  // ---- RegionA (20 MB, time-aliased; no memset, no atomics) ----
  float* q_p      = (float*)(ws + 0);            // [16][32][2048]
  float* qk_p     = (float*)(ws + 0);            // [16][80][2048]
  float* scores_p = (float*)(ws + 0);            // [4][4][80][4096]
  float* w_p      = (float*)(ws + 0);            // [4][8][80][2048]
  float* outB_p   = (float*)(ws + 0);            // [16][80][2048]
  float* ext_p    = (float*)(ws + 0);            // [16][80][2048]
  float* gate_p   = (float*)(ws + 0);            // [8][64][4096]
  float* up_p     = (float*)(ws + 8388608);      // [8][64][4096]
  float* ffn_p    = (float*)(ws + 0);            // [16][64][2048]
  // ---- persistents ----
  __bf16* Q2    = (__bf16*)(ws + 21102592);      // 80*2048
  __bf16* qk_bf = (__bf16*)(ws + 21430272);      // 80*2048
  __bf16* attn  = (__bf16*)(ws + 21757952);      // 4*80*4096
  __bf16* Apack = (__bf16*)(ws + 24379392);      // 4*80*2048
  __bf16* outB  = (__bf16*)(ws + 25690112);      // 80*2048
  float*  extracted = (float*)(ws + 26017792);   // 80*2048 f32
  __bf16* xnb   = (__bf16*)(ws + 26673152);      // 64*2048
  __bf16* hb    = (__bf16*)(ws + 26935296);      // 64*4096
  __bf16* vi    = (__bf16*)(ws + 27459584);      // 16*4096
  __bf16* h1s   = (__bf16*)(ws + 27590656);      // 16*2048
  float*  h1_p  = (float*)(ws + 27656192);       // [16][16][2048]
  float*  h2_p  = (float*)(ws + 29753344);       // [16][16][512]

  // q = (scale*queries) @ Wq^T  (prep + scale folded into A-load)
  gemm_qA<<<dim3(32, 16), 256, 0, stream>>>(queries, Wq, q_p);
  k_mkQ2<<<640, 256, 0, stream>>>(q_p, Q2);
  // qk = Q2 @ Wk
  gemm_abnat<5, 4><<<dim3(32, 16, 1), 256, 0, stream>>>(Q2, 0, 2048, Wk, 0, qk_p, 0, 2048);
  k_mkqk<<<640, 256, 0, stream>>>(qk_p, qk_bf);
  // pass1: scores_t[y][b][qh][s] = hs @ qk^T
  gemm_pass1<16><<<dim3(64, 4, 4), 256, 0, stream>>>(hs, qk_bf, scores_p);
  k_softmax<<<dim3(80, 4), 256, 0, stream>>>(scores_p, attn);
  // pass3: weighted = attn @ hs
  gemm_abnat<5, 16><<<dim3(32, 8, 4), 256, 0, stream>>>(attn, 80L * 4096, 4096,
      hs, (long)SS * HH, w_p, 8L * 80 * 2048, 2048);
  k_pack_wv<<<2560, 256, 0, stream>>>(w_p, Apack);
  // V projection (block-diag by head)
  gemm_bt<5, 4, true><<<dim3(32, 16, 1), 256, 0, stream>>>(Apack, 2048, Wv, outB_p, Wv, outB_p, 2048);
  k_sum_outB<<<640, 256, 0, stream>>>(outB_p, outB);
  // O projection
  gemm_bt<5, 4, false><<<dim3(32, 16, 1), 256, 0, stream>>>(outB, 2048, Wo, ext_p, Wo, ext_p, 2048);
  k_rms<<<96, 256, 0, stream>>>(ext_p, ln_w, hs, extracted, xnb, vi);
  // FFN up+gate + value-MLP layer 1 (merged launch)
  k_ffn1<<<1536, 256, 0, stream>>>(xnb, Wgate, Wup, gate_p, up_p, vi, V1, h1_p);
  k_act2<<<1152, 256, 0, stream>>>(gate_p, up_p, hb, h1_p, b1, h1s);
  // FFN down + value-MLP layer 2 (merged launch)
  k_ffn2<<<640, 256, 0, stream>>>(hb, Wdown, ffn_p, h1s, V2, h2_p);
  // outputs
  k_epilogue<<<72, 256, 0, stream>>>(extracted, ffn_p, h2_p, Wp, bp, Wh, bh, b2, V3, b3, out);
  k_scanentries<<<128, 256, 0, stream>>>(buf_pri, buf_ent, out);
}